// Round 2
// baseline (565.148 us; speedup 1.0000x reference)
//
#include <hip/hip_runtime.h>
#include <hip/hip_bf16.h>

typedef __attribute__((ext_vector_type(8))) short short8;
typedef __attribute__((ext_vector_type(4))) short short4v;
typedef __attribute__((ext_vector_type(4))) float floatx4;

#define M_DIM 8192
#define N_DIM 4096
#define K_DIM 4096
#define BK 64

__device__ __constant__ float NF4_TAB[16] = {
    -1.0f, -0.6961928009986877f, -0.5250730514526367f, -0.39491748809814453f,
    -0.28444138169288635f, -0.18477343022823334f, -0.09105003625154495f, 0.0f,
    0.07958029955625534f, 0.16093020141124725f, 0.24611230194568634f,
    0.33791524171829224f, 0.44070982933044434f, 0.5626170039176941f,
    0.7229568362236023f, 1.0f};

// Merged prep: blocks [0,1024) dequant W_eff; blocks [1024,17408) cast x->bf16.
// Merging lets the small dequant grid overlap with the streaming cast and
// drops one launch gap.
__global__ __launch_bounds__(256)
void prep_kernel(const float* __restrict__ x, short8* __restrict__ xb,
                 const int* __restrict__ codes,
                 const float* __restrict__ scales,
                 const float* __restrict__ la, const float* __restrict__ lb,
                 short4v* __restrict__ W) {
    __shared__ float tab[16];
    const int bid = blockIdx.x;
    if (bid < 1024) {
        // ---- dequant + LoRA-fold path ----
        if (threadIdx.x < 16) tab[threadIdx.x] = NF4_TAB[threadIdx.x];
        __syncthreads();

        const int kb = bid & 3;                 // 4 k-blocks of 1024
        const int n0 = (bid >> 2) << 4;         // 16 n-rows per block
        const int k0 = kb * 1024 + threadIdx.x * 4;

        float4 a[16];
#pragma unroll
        for (int r = 0; r < 16; r++)
            a[r] = *(const float4*)(la + (size_t)r * K_DIM + k0);

#pragma unroll 4
        for (int i = 0; i < 16; i++) {
            const int n = n0 + i;
            int4 c = *(const int4*)(codes + (size_t)n * K_DIM + k0);
            float s = scales[(n << 6) + (k0 >> 6)];
            const float* bp = lb + (n << 4);    // wave-uniform -> s_load
            float acc0 = 0.f, acc1 = 0.f, acc2 = 0.f, acc3 = 0.f;
#pragma unroll
            for (int r = 0; r < 16; r++) {
                float br = bp[r];
                acc0 += br * a[r].x;
                acc1 += br * a[r].y;
                acc2 += br * a[r].z;
                acc3 += br * a[r].w;
            }
            union { short4v v; __hip_bfloat16 h[4]; } u;
            u.h[0] = __float2bfloat16(tab[c.x] * s + 2.0f * acc0);
            u.h[1] = __float2bfloat16(tab[c.y] * s + 2.0f * acc1);
            u.h[2] = __float2bfloat16(tab[c.z] * s + 2.0f * acc2);
            u.h[3] = __float2bfloat16(tab[c.w] * s + 2.0f * acc3);
            W[((size_t)n * K_DIM + k0) >> 2] = u.v;
        }
    } else {
        // ---- fp32 -> bf16 cast path ----
        const int g = (bid - 1024) * 256 + threadIdx.x;
        const float4* xp = (const float4*)(x + (size_t)g * 8);
        float4 v0 = xp[0], v1 = xp[1];
        union { short8 v; __hip_bfloat16 h[8]; } u;
        u.h[0] = __float2bfloat16(v0.x);
        u.h[1] = __float2bfloat16(v0.y);
        u.h[2] = __float2bfloat16(v0.z);
        u.h[3] = __float2bfloat16(v0.w);
        u.h[4] = __float2bfloat16(v1.x);
        u.h[5] = __float2bfloat16(v1.y);
        u.h[6] = __float2bfloat16(v1.z);
        u.h[7] = __float2bfloat16(v1.w);
        xb[g] = u.v;
    }
}

#define GL2LDS(gsrc, ldst)                                                   \
    __builtin_amdgcn_global_load_lds(                                        \
        (const __attribute__((address_space(1))) void*)(gsrc),               \
        (__attribute__((address_space(3))) void*)(ldst), 16, 0, 0)

// ---------------------------------------------------------------------------
// 256x256 tile, BK=64, 8 waves (2M x 4N), double-buffered LDS (128 KiB),
// 8-phase schedule with ROTATED fragment reads: every ds_read is issued
// >=1 phase (2 barriers + 16 MFMAs) before its consuming MFMA, so the
// compiler's counted lgkmcnt waits are near-zero. Counted vmcnt(4) once per
// K-tile (never 0 in main loop). Swizzle: 16B-block XOR with (row&7) on
// pre-swizzled global source + ds_read addrs.  C = A * B^T.
// ---------------------------------------------------------------------------

#define STAGE_A(D, H, T) do {                                                 \
    GL2LDS(gA0 + (size_t)((H) * 128) * K_DIM + (T) * BK,                      \
           ldsA + (D) * 32768 + (H) * 16384 + ldsw);                          \
    GL2LDS(gA0 + (size_t)((H) * 128 + 64) * K_DIM + (T) * BK,                 \
           ldsA + (D) * 32768 + (H) * 16384 + 8192 + ldsw);                   \
} while (0)

#define STAGE_B(D, H, T) do {                                                 \
    GL2LDS(gB0 + (size_t)((H) * 128) * K_DIM + (T) * BK,                      \
           ldsB + (D) * 32768 + (H) * 16384 + ldsw);                          \
    GL2LDS(gB0 + (size_t)((H) * 128 + 64) * K_DIM + (T) * BK,                 \
           ldsB + (D) * 32768 + (H) * 16384 + 8192 + ldsw);                   \
} while (0)

// fragment reads (plain C++ LDS loads -> compiler emits exact lgkm waits)
#define READ_AF0(D) do {                                                      \
    _Pragma("unroll") for (int mi_ = 0; mi_ < 4; mi_++) {                     \
        int o_ = (D) * 32768 + aoff + mi_ * 2048;                             \
        af0[mi_][0] = *(const short8*)(ldsA + o_);                            \
        af0[mi_][1] = *(const short8*)(ldsA + (o_ ^ 64));                     \
    }                                                                         \
} while (0)

#define READ_AF1(D) do {                                                      \
    _Pragma("unroll") for (int mi_ = 0; mi_ < 4; mi_++) {                     \
        int o_ = (D) * 32768 + aoff + 8192 + mi_ * 2048;                      \
        af1[mi_][0] = *(const short8*)(ldsA + o_);                            \
        af1[mi_][1] = *(const short8*)(ldsA + (o_ ^ 64));                     \
    }                                                                         \
} while (0)

#define READ_BF0(D) do {                                                      \
    _Pragma("unroll") for (int ni_ = 0; ni_ < 2; ni_++) {                     \
        int o_ = (D) * 32768 + boff + ni_ * 2048;                             \
        bf0[ni_][0] = *(const short8*)(ldsB + o_);                            \
        bf0[ni_][1] = *(const short8*)(ldsB + (o_ ^ 64));                     \
    }                                                                         \
} while (0)

#define READ_BF1(D) do {                                                      \
    _Pragma("unroll") for (int ni_ = 0; ni_ < 2; ni_++) {                     \
        int o_ = (D) * 32768 + boff + 4096 + ni_ * 2048;                      \
        bf1[ni_][0] = *(const short8*)(ldsB + o_);                            \
        bf1[ni_][1] = *(const short8*)(ldsB + (o_ ^ 64));                     \
    }                                                                         \
} while (0)

#define MFMA_Q(AF, BF, MB, NB) do {                                           \
    _Pragma("unroll") for (int mi_ = 0; mi_ < 4; mi_++)                       \
    _Pragma("unroll") for (int ni_ = 0; ni_ < 2; ni_++)                       \
    _Pragma("unroll") for (int ks_ = 0; ks_ < 2; ks_++)                       \
        acc[(MB) + mi_][(NB) + ni_] =                                         \
            __builtin_amdgcn_mfma_f32_16x16x32_bf16(                          \
                AF[mi_][ks_], BF[ni_][ks_], acc[(MB) + mi_][(NB) + ni_],      \
                0, 0, 0);                                                     \
} while (0)

#define VM4   asm volatile("s_waitcnt vmcnt(4)" ::: "memory")
#define VM0   asm volatile("s_waitcnt vmcnt(0)" ::: "memory")
#define VMNONE do {} while (0)

// One K-tile = 4 phases. Quadrants: P1(af0,bf0) P2(af1,bf0) P3(af0,bf1) P4(af1,bf1)
// Reads:  P1: af1(8)   P2: bf1(4)   P3: -      P4: next af0+bf0(12, after VM+bar)
// Stages: P1: B0(T+1)  P2: B1(T+1)  P3: A0(T+2)  P4: A1(T+2)
// Region ledger: every staged region's last reader COMPLETED >=2 barriers
// before the stage issue; P4 prefetch reads (buf D^1) follow VM which drains
// through B1(T+1).
#define TILE(T, D, DOB, DOA, VM, DOPF) do {                                   \
    READ_AF1(D);                                                              \
    if (DOB) STAGE_B((D) ^ 1, 0, (T) + 1);                                    \
    __builtin_amdgcn_s_barrier();                                             \
    __builtin_amdgcn_s_setprio(1);                                            \
    MFMA_Q(af0, bf0, 0, 0);                                                   \
    __builtin_amdgcn_s_setprio(0);                                            \
    __builtin_amdgcn_s_barrier();                                             \
    READ_BF1(D);                                                              \
    if (DOB) STAGE_B((D) ^ 1, 1, (T) + 1);                                    \
    __builtin_amdgcn_s_barrier();                                             \
    __builtin_amdgcn_s_setprio(1);                                            \
    MFMA_Q(af1, bf0, 4, 0);                                                   \
    __builtin_amdgcn_s_setprio(0);                                            \
    __builtin_amdgcn_s_barrier();                                             \
    if (DOA) STAGE_A((D), 0, (T) + 2);                                        \
    __builtin_amdgcn_s_barrier();                                             \
    __builtin_amdgcn_s_setprio(1);                                            \
    MFMA_Q(af0, bf1, 0, 2);                                                   \
    __builtin_amdgcn_s_setprio(0);                                            \
    __builtin_amdgcn_s_barrier();                                             \
    if (DOA) STAGE_A((D), 1, (T) + 2);                                        \
    VM;                                                                       \
    __builtin_amdgcn_s_barrier();                                             \
    if (DOPF) { READ_AF0((D) ^ 1); READ_BF0((D) ^ 1); }                       \
    __builtin_amdgcn_s_setprio(1);                                            \
    MFMA_Q(af1, bf1, 4, 2);                                                   \
    __builtin_amdgcn_s_setprio(0);                                            \
    __builtin_amdgcn_s_barrier();                                             \
} while (0)

__global__ __launch_bounds__(512, 2)
void gemm_bt_kernel(const __hip_bfloat16* __restrict__ A,
                    const __hip_bfloat16* __restrict__ B,
                    float* __restrict__ C) {
    __shared__ __align__(16) char lds[131072];
    char* ldsA = (char*)lds;            // [2][256][64] bf16
    char* ldsB = (char*)lds + 65536;    // [2][256][64] bf16

    const int tid = threadIdx.x;
    const int wave = tid >> 6;
    const int lane = tid & 63;
    const int q = lane >> 4;
    const int t16 = lane & 15;
    const int wm = wave >> 2;           // 0..1  -> 128 rows of M
    const int wn = wave & 3;            // 0..3  -> 64 cols of N

    // bijective XCD-aware swizzle (512 blocks, 512 % 8 == 0)
    const int bid = blockIdx.x;
    const int swz = ((bid & 7) << 6) | (bid >> 3);
    const int bm0 = (swz >> 4) << 8;
    const int bn0 = (swz & 15) << 8;

    // ds_read per-lane base byte offsets within one 32 KiB buffer
    const int sw = (q ^ (t16 & 7)) << 4;
    const int aoff = (wm * 128 + t16) * 128 + sw;
    const int boff = (wn * 64 + t16) * 128 + sw;

    // staging: thread covers LDS linear bytes (j*512+tid)*16, j = 0,1
    const int r0 = tid >> 3;
    const int c0 = ((tid & 7) ^ (r0 & 7)) << 3;
    const __hip_bfloat16* gA0 = A + (size_t)(bm0 + r0) * K_DIM + c0;
    const __hip_bfloat16* gB0 = B + (size_t)(bn0 + r0) * K_DIM + c0;
    const int ldsw = wave << 10;        // wave-uniform LDS base (+lane*16 by HW)

    floatx4 acc[8][4] = {};
    short8 af0[4][2], af1[4][2], bf0[2][2], bf1[2][2];

    // prologue: tile0 all halves + tile1 A halves; VM4 leaves A(1) in flight
    STAGE_A(0, 0, 0); STAGE_A(0, 1, 0);
    STAGE_B(0, 0, 0); STAGE_B(0, 1, 0);
    STAGE_A(1, 0, 1); STAGE_A(1, 1, 1);
    VM4;
    __builtin_amdgcn_s_barrier();
    READ_AF0(0);
    READ_BF0(0);

#pragma unroll 1
    for (int tp = 0; tp < 31; ++tp) {
        const int t2 = tp << 1;
        TILE(t2, 0, 1, 1, VM4, 1);
        TILE(t2 + 1, 1, 1, 1, VM4, 1);
    }
    TILE(62, 0, 1, 0, VM0, 1);
    TILE(63, 1, 0, 0, VMNONE, 0);

    // C/D layout: col = lane&15, row = (lane>>4)*4 + reg (m89/m91 verified)
#pragma unroll
    for (int mi = 0; mi < 8; mi++) {
        int row0 = bm0 + wm * 128 + mi * 16 + q * 4;
#pragma unroll
        for (int ni = 0; ni < 4; ni++) {
            int col = bn0 + wn * 64 + ni * 16 + t16;
            float* cp = C + (size_t)row0 * N_DIM + col;
#pragma unroll
            for (int r = 0; r < 4; r++) cp[(size_t)r * N_DIM] = acc[mi][ni][r];
        }
    }
}

extern "C" void kernel_launch(void* const* d_in, const int* in_sizes, int n_in,
                              void* d_out, int out_size, void* d_ws,
                              size_t ws_size, hipStream_t stream) {
    const float* x = (const float*)d_in[0];
    const int* codes = (const int*)d_in[1];
    const float* scales = (const float*)d_in[2];
    const float* loraA = (const float*)d_in[3];
    const float* loraB = (const float*)d_in[4];
    float* out = (float*)d_out;

    char* ws = (char*)d_ws;
    __hip_bfloat16* xb = (__hip_bfloat16*)ws;                    // 64 MiB
    __hip_bfloat16* Wb = (__hip_bfloat16*)(ws + 67108864);       // 32 MiB

    prep_kernel<<<dim3(1024 + 16384), dim3(256), 0, stream>>>(
        x, (short8*)xb, codes, scales, loraA, loraB, (short4v*)Wb);
    gemm_bt_kernel<<<dim3(512), dim3(512), 0, stream>>>(xb, Wb, out);
}

// Round 3
// 504.060 us; speedup vs baseline: 1.1212x; 1.1212x over previous
//
#include <hip/hip_runtime.h>
#include <hip/hip_bf16.h>

typedef __attribute__((ext_vector_type(8))) short short8;
typedef __attribute__((ext_vector_type(4))) short short4v;
typedef __attribute__((ext_vector_type(4))) float floatx4;

#define M_DIM 8192
#define N_DIM 4096
#define K_DIM 4096
#define BK 64

__device__ __constant__ float NF4_TAB[16] = {
    -1.0f, -0.6961928009986877f, -0.5250730514526367f, -0.39491748809814453f,
    -0.28444138169288635f, -0.18477343022823334f, -0.09105003625154495f, 0.0f,
    0.07958029955625534f, 0.16093020141124725f, 0.24611230194568634f,
    0.33791524171829224f, 0.44070982933044434f, 0.5626170039176941f,
    0.7229568362236023f, 1.0f};

// W_eff[n][k] = NF4[code]*scale + 2*sum_r loraB[n][r]*loraA[r][k], as bf16.
__global__ __launch_bounds__(256)
void dequant_lora_kernel(const int* __restrict__ codes,
                         const float* __restrict__ scales,
                         const float* __restrict__ la,
                         const float* __restrict__ lb,
                         short4v* __restrict__ W) {
    __shared__ float tab[16];
    if (threadIdx.x < 16) tab[threadIdx.x] = NF4_TAB[threadIdx.x];
    __syncthreads();

    const int kb = blockIdx.x & 3;                 // 4 k-blocks of 1024
    const int n0 = (blockIdx.x >> 2) << 4;         // 16 n-rows per block
    const int k0 = kb * 1024 + threadIdx.x * 4;

    float4 a[16];
#pragma unroll
    for (int r = 0; r < 16; r++)
        a[r] = *(const float4*)(la + (size_t)r * K_DIM + k0);

#pragma unroll 4
    for (int i = 0; i < 16; i++) {
        const int n = n0 + i;
        int4 c = *(const int4*)(codes + (size_t)n * K_DIM + k0);
        float s = scales[(n << 6) + (k0 >> 6)];
        const float* bp = lb + (n << 4);           // wave-uniform -> s_load
        float acc0 = 0.f, acc1 = 0.f, acc2 = 0.f, acc3 = 0.f;
#pragma unroll
        for (int r = 0; r < 16; r++) {
            float br = bp[r];
            acc0 += br * a[r].x;
            acc1 += br * a[r].y;
            acc2 += br * a[r].z;
            acc3 += br * a[r].w;
        }
        union { short4v v; __hip_bfloat16 h[4]; } u;
        u.h[0] = __float2bfloat16(tab[c.x] * s + 2.0f * acc0);
        u.h[1] = __float2bfloat16(tab[c.y] * s + 2.0f * acc1);
        u.h[2] = __float2bfloat16(tab[c.z] * s + 2.0f * acc2);
        u.h[3] = __float2bfloat16(tab[c.w] * s + 2.0f * acc3);
        W[((size_t)n * K_DIM + k0) >> 2] = u.v;
    }
}

// fp32 -> bf16 cast, 8 elements per thread
__global__ void cast_x_kernel(const float* __restrict__ x,
                              short8* __restrict__ xb) {
    int g = blockIdx.x * blockDim.x + threadIdx.x;
    const float4* xp = (const float4*)(x + (size_t)g * 8);
    float4 v0 = xp[0], v1 = xp[1];
    union { short8 v; __hip_bfloat16 h[8]; } u;
    u.h[0] = __float2bfloat16(v0.x);
    u.h[1] = __float2bfloat16(v0.y);
    u.h[2] = __float2bfloat16(v0.z);
    u.h[3] = __float2bfloat16(v0.w);
    u.h[4] = __float2bfloat16(v1.x);
    u.h[5] = __float2bfloat16(v1.y);
    u.h[6] = __float2bfloat16(v1.z);
    u.h[7] = __float2bfloat16(v1.w);
    xb[g] = u.v;
}

#define GL2LDS(gsrc, ldst)                                                   \
    __builtin_amdgcn_global_load_lds(                                        \
        (const __attribute__((address_space(1))) void*)(gsrc),               \
        (__attribute__((address_space(3))) void*)(ldst), 16, 0, 0)

// ---------------------------------------------------------------------------
// 256x256 tile, BK=64, 8 waves (2M x 4N), double-buffered LDS (128 KiB).
// R1 phase structure (reads phase-local, proven 51% MfmaUtil) with DEEPER
// staging: during tile t (buf D) stage BOTH A(t+2) and B(t+2) into buf D
// (A-region free after P2's reads, B-region free after P3's reads).
// vmcnt(8) at P4 then only waits on tile-(t+1) loads issued >=4 phases
// earlier (landed), keeping tile-(t+2)'s 8 loads in flight.
// Swizzle: 16B-block XOR with (row&7) on pre-swizzled global source +
// ds_read addrs (0 bank conflicts measured).  C = A * B^T.
// ---------------------------------------------------------------------------

#define STAGE_A(D, H, T) do {                                                 \
    GL2LDS(gA0 + (size_t)((H) * 128) * K_DIM + (T) * BK,                      \
           ldsA + (D) * 32768 + (H) * 16384 + ldsw);                          \
    GL2LDS(gA0 + (size_t)((H) * 128 + 64) * K_DIM + (T) * BK,                 \
           ldsA + (D) * 32768 + (H) * 16384 + 8192 + ldsw);                   \
} while (0)

#define STAGE_B(D, H, T) do {                                                 \
    GL2LDS(gB0 + (size_t)((H) * 128) * K_DIM + (T) * BK,                      \
           ldsB + (D) * 32768 + (H) * 16384 + ldsw);                          \
    GL2LDS(gB0 + (size_t)((H) * 128 + 64) * K_DIM + (T) * BK,                 \
           ldsB + (D) * 32768 + (H) * 16384 + 8192 + ldsw);                   \
} while (0)

#define READ_AF0(D) do {                                                      \
    _Pragma("unroll") for (int mi_ = 0; mi_ < 4; mi_++) {                     \
        int o_ = (D) * 32768 + aoff + mi_ * 2048;                             \
        af0[mi_][0] = *(const short8*)(ldsA + o_);                            \
        af0[mi_][1] = *(const short8*)(ldsA + (o_ ^ 64));                     \
    }                                                                         \
} while (0)

#define READ_AF1(D) do {                                                      \
    _Pragma("unroll") for (int mi_ = 0; mi_ < 4; mi_++) {                     \
        int o_ = (D) * 32768 + aoff + 8192 + mi_ * 2048;                      \
        af1[mi_][0] = *(const short8*)(ldsA + o_);                            \
        af1[mi_][1] = *(const short8*)(ldsA + (o_ ^ 64));                     \
    }                                                                         \
} while (0)

#define READ_BF0(D) do {                                                      \
    _Pragma("unroll") for (int ni_ = 0; ni_ < 2; ni_++) {                     \
        int o_ = (D) * 32768 + boff + ni_ * 2048;                             \
        bf0[ni_][0] = *(const short8*)(ldsB + o_);                            \
        bf0[ni_][1] = *(const short8*)(ldsB + (o_ ^ 64));                     \
    }                                                                         \
} while (0)

#define READ_BF1(D) do {                                                      \
    _Pragma("unroll") for (int ni_ = 0; ni_ < 2; ni_++) {                     \
        int o_ = (D) * 32768 + boff + 4096 + ni_ * 2048;                      \
        bf1[ni_][0] = *(const short8*)(ldsB + o_);                            \
        bf1[ni_][1] = *(const short8*)(ldsB + (o_ ^ 64));                     \
    }                                                                         \
} while (0)

#define MFMA_Q(AF, BF, MB, NB) do {                                           \
    _Pragma("unroll") for (int mi_ = 0; mi_ < 4; mi_++)                       \
    _Pragma("unroll") for (int ni_ = 0; ni_ < 2; ni_++)                       \
    _Pragma("unroll") for (int ks_ = 0; ks_ < 2; ks_++)                       \
        acc[(MB) + mi_][(NB) + ni_] =                                         \
            __builtin_amdgcn_mfma_f32_16x16x32_bf16(                          \
                AF[mi_][ks_], BF[ni_][ks_], acc[(MB) + mi_][(NB) + ni_],      \
                0, 0, 0);                                                     \
} while (0)

#define LGKM0 asm volatile("s_waitcnt lgkmcnt(0)" ::: "memory")
#define VM8   asm volatile("s_waitcnt vmcnt(8)" ::: "memory")
#define VM0   asm volatile("s_waitcnt vmcnt(0)" ::: "memory")
#define VMNONE do {} while (0)

// One K-tile = 4 phases. Quadrants: P1(af0,bf0) P2(af1,bf0) P3(af0,bf1) P4(af1,bf1)
// Stages (into CURRENT buf D, for tile T+2):
//   P3: A0(T+2)   [A-region reads completed at P2]
//   P4: A1(T+2), B0(T+2), B1(T+2)   [B-region reads completed at P3]
// vmcnt(8) at P4 waits only on tile-(T+1)'s 8 loads (issued one full tile
// earlier), leaving tile-(T+2)'s 8 in flight across the tile boundary.
#define TILE(T, D, DO, VM) do {                                               \
    short8 af0[4][2], af1[4][2], bf0[2][2], bf1[2][2];                        \
    /* P1 */                                                                  \
    READ_AF0(D); READ_BF0(D);                                                 \
    __builtin_amdgcn_s_barrier();                                             \
    LGKM0;                                                                    \
    __builtin_amdgcn_s_setprio(1);                                            \
    MFMA_Q(af0, bf0, 0, 0);                                                   \
    __builtin_amdgcn_s_setprio(0);                                            \
    __builtin_amdgcn_s_barrier();                                             \
    /* P2 */                                                                  \
    READ_AF1(D);                                                              \
    __builtin_amdgcn_s_barrier();                                             \
    LGKM0;                                                                    \
    __builtin_amdgcn_s_setprio(1);                                            \
    MFMA_Q(af1, bf0, 4, 0);                                                   \
    __builtin_amdgcn_s_setprio(0);                                            \
    __builtin_amdgcn_s_barrier();                                             \
    /* P3 */                                                                  \
    READ_BF1(D);                                                              \
    if (DO) STAGE_A(D, 0, (T) + 2);                                           \
    __builtin_amdgcn_s_barrier();                                             \
    LGKM0;                                                                    \
    __builtin_amdgcn_s_setprio(1);                                            \
    MFMA_Q(af0, bf1, 0, 2);                                                   \
    __builtin_amdgcn_s_setprio(0);                                            \
    __builtin_amdgcn_s_barrier();                                             \
    /* P4 */                                                                  \
    if (DO) { STAGE_A(D, 1, (T) + 2); STAGE_B(D, 0, (T) + 2);                 \
              STAGE_B(D, 1, (T) + 2); }                                       \
    VM;                                                                       \
    __builtin_amdgcn_s_barrier();                                             \
    __builtin_amdgcn_s_setprio(1);                                            \
    MFMA_Q(af1, bf1, 4, 2);                                                   \
    __builtin_amdgcn_s_setprio(0);                                            \
    __builtin_amdgcn_s_barrier();                                             \
} while (0)

__global__ __launch_bounds__(512, 2)
void gemm_bt_kernel(const __hip_bfloat16* __restrict__ A,
                    const __hip_bfloat16* __restrict__ B,
                    float* __restrict__ C) {
    __shared__ __align__(16) char lds[131072];
    char* ldsA = (char*)lds;            // [2][256][64] bf16
    char* ldsB = (char*)lds + 65536;    // [2][256][64] bf16

    const int tid = threadIdx.x;
    const int wave = tid >> 6;
    const int lane = tid & 63;
    const int q = lane >> 4;
    const int t16 = lane & 15;
    const int wm = wave >> 2;           // 0..1  -> 128 rows of M
    const int wn = wave & 3;            // 0..3  -> 64 cols of N

    // bijective XCD-aware swizzle (512 blocks, 512 % 8 == 0)
    const int bid = blockIdx.x;
    const int swz = ((bid & 7) << 6) | (bid >> 3);
    const int bm0 = (swz >> 4) << 8;
    const int bn0 = (swz & 15) << 8;

    // ds_read per-lane base byte offsets within one 32 KiB buffer
    const int sw = (q ^ (t16 & 7)) << 4;
    const int aoff = (wm * 128 + t16) * 128 + sw;
    const int boff = (wn * 64 + t16) * 128 + sw;

    // staging: thread covers LDS linear bytes (j*512+tid)*16, j = 0,1
    const int r0 = tid >> 3;
    const int c0 = ((tid & 7) ^ (r0 & 7)) << 3;
    const __hip_bfloat16* gA0 = A + (size_t)(bm0 + r0) * K_DIM + c0;
    const __hip_bfloat16* gB0 = B + (size_t)(bn0 + r0) * K_DIM + c0;
    const int ldsw = wave << 10;        // wave-uniform LDS base (+lane*16 by HW)

    floatx4 acc[8][4] = {};

    // prologue: stage tiles 0 and 1 fully; drain tile 0, keep tile 1 in flight
    STAGE_A(0, 0, 0); STAGE_A(0, 1, 0);
    STAGE_B(0, 0, 0); STAGE_B(0, 1, 0);
    STAGE_A(1, 0, 1); STAGE_A(1, 1, 1);
    STAGE_B(1, 0, 1); STAGE_B(1, 1, 1);
    VM8;
    __builtin_amdgcn_s_barrier();

#pragma unroll 1
    for (int tp = 0; tp < 31; ++tp) {
        const int t2 = tp << 1;
        TILE(t2, 0, 1, VM8);
        TILE(t2 + 1, 1, 1, VM8);
    }
    TILE(62, 0, 0, VM0);
    TILE(63, 1, 0, VMNONE);

    // C/D layout: col = lane&15, row = (lane>>4)*4 + reg (m89/m91 verified)
#pragma unroll
    for (int mi = 0; mi < 8; mi++) {
        int row0 = bm0 + wm * 128 + mi * 16 + q * 4;
#pragma unroll
        for (int ni = 0; ni < 4; ni++) {
            int col = bn0 + wn * 64 + ni * 16 + t16;
            float* cp = C + (size_t)row0 * N_DIM + col;
#pragma unroll
            for (int r = 0; r < 4; r++) cp[(size_t)r * N_DIM] = acc[mi][ni][r];
        }
    }
}

extern "C" void kernel_launch(void* const* d_in, const int* in_sizes, int n_in,
                              void* d_out, int out_size, void* d_ws,
                              size_t ws_size, hipStream_t stream) {
    const float* x = (const float*)d_in[0];
    const int* codes = (const int*)d_in[1];
    const float* scales = (const float*)d_in[2];
    const float* loraA = (const float*)d_in[3];
    const float* loraB = (const float*)d_in[4];
    float* out = (float*)d_out;

    char* ws = (char*)d_ws;
    __hip_bfloat16* xb = (__hip_bfloat16*)ws;                    // 64 MiB
    __hip_bfloat16* Wb = (__hip_bfloat16*)(ws + 67108864);       // 32 MiB

    dequant_lora_kernel<<<dim3(4 * (N_DIM / 16)), dim3(256), 0, stream>>>(
        codes, scales, loraA, loraB, (short4v*)Wb);
    cast_x_kernel<<<dim3((M_DIM * (K_DIM / 8)) / 256), dim3(256), 0, stream>>>(
        x, (short8*)xb);
    gemm_bt_kernel<<<dim3(512), dim3(512), 0, stream>>>(xb, Wb, out);
}

// Round 5
// 489.153 us; speedup vs baseline: 1.1554x; 1.0305x over previous
//
#include <hip/hip_runtime.h>
#include <hip/hip_bf16.h>

typedef __attribute__((ext_vector_type(8))) short short8;
typedef __attribute__((ext_vector_type(4))) short short4v;
typedef __attribute__((ext_vector_type(4))) float floatx4;

#define M_DIM 8192
#define N_DIM 4096
#define K_DIM 4096
#define BK 64

__device__ __constant__ float NF4_TAB[16] = {
    -1.0f, -0.6961928009986877f, -0.5250730514526367f, -0.39491748809814453f,
    -0.28444138169288635f, -0.18477343022823334f, -0.09105003625154495f, 0.0f,
    0.07958029955625534f, 0.16093020141124725f, 0.24611230194568634f,
    0.33791524171829224f, 0.44070982933044434f, 0.5626170039176941f,
    0.7229568362236023f, 1.0f};

// W_eff[n][k] = NF4[code]*scale + 2*sum_r loraB[n][r]*loraA[r][k], as bf16.
__global__ __launch_bounds__(256)
void dequant_lora_kernel(const int* __restrict__ codes,
                         const float* __restrict__ scales,
                         const float* __restrict__ la,
                         const float* __restrict__ lb,
                         short4v* __restrict__ W) {
    __shared__ float tab[16];
    if (threadIdx.x < 16) tab[threadIdx.x] = NF4_TAB[threadIdx.x];
    __syncthreads();

    const int kb = blockIdx.x & 3;                 // 4 k-blocks of 1024
    const int n0 = (blockIdx.x >> 2) << 4;         // 16 n-rows per block
    const int k0 = kb * 1024 + threadIdx.x * 4;

    float4 a[16];
#pragma unroll
    for (int r = 0; r < 16; r++)
        a[r] = *(const float4*)(la + (size_t)r * K_DIM + k0);

#pragma unroll 4
    for (int i = 0; i < 16; i++) {
        const int n = n0 + i;
        int4 c = *(const int4*)(codes + (size_t)n * K_DIM + k0);
        float s = scales[(n << 6) + (k0 >> 6)];
        const float* bp = lb + (n << 4);           // wave-uniform -> s_load
        float acc0 = 0.f, acc1 = 0.f, acc2 = 0.f, acc3 = 0.f;
#pragma unroll
        for (int r = 0; r < 16; r++) {
            float br = bp[r];
            acc0 += br * a[r].x;
            acc1 += br * a[r].y;
            acc2 += br * a[r].z;
            acc3 += br * a[r].w;
        }
        union { short4v v; __hip_bfloat16 h[4]; } u;
        u.h[0] = __float2bfloat16(tab[c.x] * s + 2.0f * acc0);
        u.h[1] = __float2bfloat16(tab[c.y] * s + 2.0f * acc1);
        u.h[2] = __float2bfloat16(tab[c.z] * s + 2.0f * acc2);
        u.h[3] = __float2bfloat16(tab[c.w] * s + 2.0f * acc3);
        W[((size_t)n * K_DIM + k0) >> 2] = u.v;
    }
}

// fp32 -> bf16 cast, 8 elements per thread
__global__ void cast_x_kernel(const float* __restrict__ x,
                              short8* __restrict__ xb) {
    int g = blockIdx.x * blockDim.x + threadIdx.x;
    const float4* xp = (const float4*)(x + (size_t)g * 8);
    float4 v0 = xp[0], v1 = xp[1];
    union { short8 v; __hip_bfloat16 h[8]; } u;
    u.h[0] = __float2bfloat16(v0.x);
    u.h[1] = __float2bfloat16(v0.y);
    u.h[2] = __float2bfloat16(v0.z);
    u.h[3] = __float2bfloat16(v0.w);
    u.h[4] = __float2bfloat16(v1.x);
    u.h[5] = __float2bfloat16(v1.y);
    u.h[6] = __float2bfloat16(v1.z);
    u.h[7] = __float2bfloat16(v1.w);
    xb[g] = u.v;
}

#define GL2LDS(gsrc, ldst)                                                   \
    __builtin_amdgcn_global_load_lds(                                        \
        (const __attribute__((address_space(1))) void*)(gsrc),               \
        (__attribute__((address_space(3))) void*)(ldst), 16, 0, 0)

// ---------------------------------------------------------------------------
// 256x256 tile, BK=64, 8 waves (2M x 4N), double-buffered LDS (128 KiB).
// Even-spread deep prefetch (m201-style vmcnt(6)):
//   P1(t): stage A1(t+1) -> buf D^1, half 1   (region dead since P2(t-1))
//   P3(t): stage A0(t+2) -> buf D,   half 0   (A reads of tile t end at P2)
//   P4(t): stage B0,B1(t+2) -> buf D          (B reads of tile t end at P3)
//   VM6 at P4(t): drains ALL 8 loads of tile t+1 (slacks 3/4/5 phases),
//   retains {A0(t+2), B0B1(t+2)} = 6. Loads never drain to 0 in main loop.
// KEY constraint (R4 lesson): af0/bf0 at P1 span BOTH staged halves, so all
// of tile t+1's loads must drain at the single P4(t) wait.
// Swizzle: 16B-block XOR with (row&7) on pre-swizzled global source +
// ds_read addrs (0 bank conflicts measured).  C = A * B^T.
// ---------------------------------------------------------------------------

#define STAGE_A(D, H, T) do {                                                 \
    GL2LDS(gA0 + (size_t)((H) * 128) * K_DIM + (T) * BK,                      \
           ldsA + (D) * 32768 + (H) * 16384 + ldsw);                          \
    GL2LDS(gA0 + (size_t)((H) * 128 + 64) * K_DIM + (T) * BK,                 \
           ldsA + (D) * 32768 + (H) * 16384 + 8192 + ldsw);                   \
} while (0)

#define STAGE_B(D, H, T) do {                                                 \
    GL2LDS(gB0 + (size_t)((H) * 128) * K_DIM + (T) * BK,                      \
           ldsB + (D) * 32768 + (H) * 16384 + ldsw);                          \
    GL2LDS(gB0 + (size_t)((H) * 128 + 64) * K_DIM + (T) * BK,                 \
           ldsB + (D) * 32768 + (H) * 16384 + 8192 + ldsw);                   \
} while (0)

#define READ_AF0(D) do {                                                      \
    _Pragma("unroll") for (int mi_ = 0; mi_ < 4; mi_++) {                     \
        int o_ = (D) * 32768 + aoff + mi_ * 2048;                             \
        af0[mi_][0] = *(const short8*)(ldsA + o_);                            \
        af0[mi_][1] = *(const short8*)(ldsA + (o_ ^ 64));                     \
    }                                                                         \
} while (0)

#define READ_AF1(D) do {                                                      \
    _Pragma("unroll") for (int mi_ = 0; mi_ < 4; mi_++) {                     \
        int o_ = (D) * 32768 + aoff + 8192 + mi_ * 2048;                      \
        af1[mi_][0] = *(const short8*)(ldsA + o_);                            \
        af1[mi_][1] = *(const short8*)(ldsA + (o_ ^ 64));                     \
    }                                                                         \
} while (0)

#define READ_BF0(D) do {                                                      \
    _Pragma("unroll") for (int ni_ = 0; ni_ < 2; ni_++) {                     \
        int o_ = (D) * 32768 + boff + ni_ * 2048;                             \
        bf0[ni_][0] = *(const short8*)(ldsB + o_);                            \
        bf0[ni_][1] = *(const short8*)(ldsB + (o_ ^ 64));                     \
    }                                                                         \
} while (0)

#define READ_BF1(D) do {                                                      \
    _Pragma("unroll") for (int ni_ = 0; ni_ < 2; ni_++) {                     \
        int o_ = (D) * 32768 + boff + 4096 + ni_ * 2048;                      \
        bf1[ni_][0] = *(const short8*)(ldsB + o_);                            \
        bf1[ni_][1] = *(const short8*)(ldsB + (o_ ^ 64));                     \
    }                                                                         \
} while (0)

#define MFMA_Q(AF, BF, MB, NB) do {                                           \
    _Pragma("unroll") for (int mi_ = 0; mi_ < 4; mi_++)                       \
    _Pragma("unroll") for (int ni_ = 0; ni_ < 2; ni_++)                       \
    _Pragma("unroll") for (int ks_ = 0; ks_ < 2; ks_++)                       \
        acc[(MB) + mi_][(NB) + ni_] =                                         \
            __builtin_amdgcn_mfma_f32_16x16x32_bf16(                          \
                AF[mi_][ks_], BF[ni_][ks_], acc[(MB) + mi_][(NB) + ni_],      \
                0, 0, 0);                                                     \
} while (0)

#define LGKM0 asm volatile("s_waitcnt lgkmcnt(0)" ::: "memory")
#define VMC6  asm volatile("s_waitcnt vmcnt(6)" ::: "memory")
#define VMC0  asm volatile("s_waitcnt vmcnt(0)" ::: "memory")
#define VMNONE do {} while (0)

// One K-tile = 4 phases. Quadrants: P1(af0,bf0) P2(af1,bf0) P3(af0,bf1) P4(af1,bf1)
// Stages: P1: A1(T+1)->D^1   P3: A0(T+2)->D   P4: B0,B1(T+2)->D
// Wait:   VM at P4 drains {A0(T+1),B0B1(T+1),A1(T+1)} (8 loads, slack 5/4/3
// phases), retaining {A0(T+2),B0B1(T+2)} = 6.
#define TILE(T, D, DOA1, DOA0, DOB, VM) do {                                  \
    short8 af0[4][2], af1[4][2], bf0[2][2], bf1[2][2];                        \
    /* P1 */                                                                  \
    READ_AF0(D); READ_BF0(D);                                                 \
    if (DOA1) STAGE_A((D) ^ 1, 1, (T) + 1);                                   \
    __builtin_amdgcn_s_barrier();                                             \
    LGKM0;                                                                    \
    __builtin_amdgcn_s_setprio(1);                                            \
    MFMA_Q(af0, bf0, 0, 0);                                                   \
    __builtin_amdgcn_s_setprio(0);                                            \
    __builtin_amdgcn_s_barrier();                                             \
    /* P2 */                                                                  \
    READ_AF1(D);                                                              \
    __builtin_amdgcn_s_barrier();                                             \
    LGKM0;                                                                    \
    __builtin_amdgcn_s_setprio(1);                                            \
    MFMA_Q(af1, bf0, 4, 0);                                                   \
    __builtin_amdgcn_s_setprio(0);                                            \
    __builtin_amdgcn_s_barrier();                                             \
    /* P3 */                                                                  \
    READ_BF1(D);                                                              \
    if (DOA0) STAGE_A(D, 0, (T) + 2);                                         \
    __builtin_amdgcn_s_barrier();                                             \
    LGKM0;                                                                    \
    __builtin_amdgcn_s_setprio(1);                                            \
    MFMA_Q(af0, bf1, 0, 2);                                                   \
    __builtin_amdgcn_s_setprio(0);                                            \
    __builtin_amdgcn_s_barrier();                                             \
    /* P4 */                                                                  \
    if (DOB) { STAGE_B(D, 0, (T) + 2); STAGE_B(D, 1, (T) + 2); }              \
    VM;                                                                       \
    __builtin_amdgcn_s_barrier();                                             \
    __builtin_amdgcn_s_setprio(1);                                            \
    MFMA_Q(af1, bf1, 4, 2);                                                   \
    __builtin_amdgcn_s_setprio(0);                                            \
    __builtin_amdgcn_s_barrier();                                             \
} while (0)

__global__ __launch_bounds__(512, 2)
void gemm_bt_kernel(const __hip_bfloat16* __restrict__ A,
                    const __hip_bfloat16* __restrict__ B,
                    float* __restrict__ C) {
    __shared__ __align__(16) char lds[131072];
    char* ldsA = (char*)lds;            // [2][256][64] bf16
    char* ldsB = (char*)lds + 65536;    // [2][256][64] bf16

    const int tid = threadIdx.x;
    const int wave = tid >> 6;
    const int lane = tid & 63;
    const int q = lane >> 4;
    const int t16 = lane & 15;
    const int wm = wave >> 2;           // 0..1  -> 128 rows of M
    const int wn = wave & 3;            // 0..3  -> 64 cols of N

    // bijective XCD-aware swizzle (512 blocks, 512 % 8 == 0)
    const int bid = blockIdx.x;
    const int swz = ((bid & 7) << 6) | (bid >> 3);
    const int bm0 = (swz >> 4) << 8;
    const int bn0 = (swz & 15) << 8;

    // ds_read per-lane base byte offsets within one 32 KiB buffer
    const int sw = (q ^ (t16 & 7)) << 4;
    const int aoff = (wm * 128 + t16) * 128 + sw;
    const int boff = (wn * 64 + t16) * 128 + sw;

    // staging: thread covers LDS linear bytes (j*512+tid)*16, j = 0,1
    const int r0 = tid >> 3;
    const int c0 = ((tid & 7) ^ (r0 & 7)) << 3;
    const __hip_bfloat16* gA0 = A + (size_t)(bm0 + r0) * K_DIM + c0;
    const __hip_bfloat16* gB0 = B + (size_t)(bn0 + r0) * K_DIM + c0;
    const int ldsw = wave << 10;        // wave-uniform LDS base (+lane*16 by HW)

    floatx4 acc[8][4] = {};

    // prologue (queue order = drain order):
    // tile0 all 4 half-tiles, then A0(1), then B0B1(1); vmcnt(6) drains
    // tile0's 8 and retains {A0(1), B0B1(1)} — the steady-state carry.
    STAGE_A(0, 0, 0); STAGE_A(0, 1, 0);
    STAGE_B(0, 0, 0); STAGE_B(0, 1, 0);
    STAGE_A(1, 0, 1);
    STAGE_B(1, 0, 1); STAGE_B(1, 1, 1);
    VMC6;
    __builtin_amdgcn_s_barrier();

#pragma unroll 1
    for (int tp = 0; tp < 31; ++tp) {
        const int t2 = tp << 1;
        TILE(t2, 0, 1, 1, 1, VMC6);
        TILE(t2 + 1, 1, 1, 1, 1, VMC6);
    }
    // T=62: stage only A1(63); drain everything. T=63: reads only.
    TILE(62, 0, 1, 0, 0, VMC0);
    TILE(63, 1, 0, 0, 0, VMNONE);

    // C/D layout: col = lane&15, row = (lane>>4)*4 + reg (m89/m91 verified)
#pragma unroll
    for (int mi = 0; mi < 8; mi++) {
        int row0 = bm0 + wm * 128 + mi * 16 + q * 4;
#pragma unroll
        for (int ni = 0; ni < 4; ni++) {
            int col = bn0 + wn * 64 + ni * 16 + t16;
            float* cp = C + (size_t)row0 * N_DIM + col;
#pragma unroll
            for (int r = 0; r < 4; r++) cp[(size_t)r * N_DIM] = acc[mi][ni][r];
        }
    }
}

extern "C" void kernel_launch(void* const* d_in, const int* in_sizes, int n_in,
                              void* d_out, int out_size, void* d_ws,
                              size_t ws_size, hipStream_t stream) {
    const float* x = (const float*)d_in[0];
    const int* codes = (const int*)d_in[1];
    const float* scales = (const float*)d_in[2];
    const float* loraA = (const float*)d_in[3];
    const float* loraB = (const float*)d_in[4];
    float* out = (float*)d_out;

    char* ws = (char*)d_ws;
    __hip_bfloat16* xb = (__hip_bfloat16*)ws;                    // 64 MiB
    __hip_bfloat16* Wb = (__hip_bfloat16*)(ws + 67108864);       // 32 MiB

    dequant_lora_kernel<<<dim3(4 * (N_DIM / 16)), dim3(256), 0, stream>>>(
        codes, scales, loraA, loraB, (short4v*)Wb);
    cast_x_kernel<<<dim3((M_DIM * (K_DIM / 8)) / 256), dim3(256), 0, stream>>>(
        x, (short8*)xb);
    gemm_bt_kernel<<<dim3(512), dim3(512), 0, stream>>>(xb, Wb, out);
}